// Round 2
// baseline (161.899 us; speedup 1.0000x reference)
//
#include <hip/hip_runtime.h>
#include <hip/hip_bf16.h>
#include <math.h>

// NT-Xent loss, fused flash-style. N=8192 rows, D=256.
//   k_norm: row L2-normalize fp32 -> bf16 (ws); zero sumexp + out
//   k_sim : bf16 MFMA, exp((sim-1)/T) in-register, per-row sum atomics
//           wave tile 32x64 (afrag 64 VGPR - no spill; R1's 64x64 spilled
//           ~180 B/lane -> 24 MB scratch WRITE_SIZE = the whole 77 us)
//   k_nll : exact fp32 pos dot + per-row nll + mean via atomicAdd
#define N_ROWS 8192
#define D_DIM  256
#define HALF_N 4096
#define INV_T      14.285714285714286f      // 1/0.07
#define SCALE_LOG2 20.609929155556620f      // log2(e)/0.07
#define NEG_SCALE  -20.609929155556620f
#define EPSV   1e-8f

typedef __attribute__((ext_vector_type(8))) short bf16x8;   // 8 bf16 = 4 VGPR
typedef __attribute__((ext_vector_type(4))) float f32x4;

#define AS1 __attribute__((address_space(1)))
#define AS3 __attribute__((address_space(3)))

__device__ inline unsigned short f2bf(float x) {
    unsigned int u = __float_as_uint(x);
    unsigned int r = (u + 0x7fffu + ((u >> 16) & 1u)) >> 16;   // RNE
    return (unsigned short)r;
}

// ---------------- kernel 1: normalize rows, emit bf16; zero accumulators ---
__global__ __launch_bounds__(256) void k_norm(const float* __restrict__ feat,
                                              unsigned short* __restrict__ fbf,
                                              float* __restrict__ sumexp,
                                              float* __restrict__ out) {
    const int tid = threadIdx.x;
    const int gid = blockIdx.x * 256 + tid;
    if (gid < N_ROWS) sumexp[gid] = 0.f;
    if (gid == 0) out[0] = 0.f;

    const int w = tid >> 6, lane = tid & 63;
    const int row = blockIdx.x * 4 + w;              // 2048 blocks * 4 rows
    const float4 v = ((const float4*)(feat + row * D_DIM))[lane];
    float ss = v.x*v.x + v.y*v.y + v.z*v.z + v.w*v.w;
    #pragma unroll
    for (int off = 32; off; off >>= 1) ss += __shfl_xor(ss, off);
    const float scale = 1.f / fmaxf(sqrtf(ss), EPSV);
    ushort4 o;
    o.x = f2bf(v.x * scale);
    o.y = f2bf(v.y * scale);
    o.z = f2bf(v.z * scale);
    o.w = f2bf(v.w * scale);
    ((ushort4*)(fbf + row * D_DIM))[lane] = o;
}

// ---------------- kernel 2: fused sim + exp + row-sum ----------------------
// grid = 2048: rt = blockIdx>>5 (64 row tiles of 128), cs = blockIdx&31
// (256-col slice). 4 waves, each owns 32 rows of the 128-row block tile.
// Per jt (4 iters): B tile 64 cols x 256 k = 32 KB LDS via global_load_lds
// w=16, XOR-16B-chunk swizzle -> conflict-free ds_read_b128 frag reads.
// A operand (32 rows x 256 k) in registers: 16 frags = 64 VGPR.
// DMA for tile jt+1 is issued before the exp epilogue of tile jt (overlap).
__global__ __launch_bounds__(256, 3) void k_sim(const unsigned short* __restrict__ fbf,
                                                float* __restrict__ sumexp) {
    __shared__ __align__(16) char Bs[32768];
    const int tid  = threadIdx.x;
    const int lane = tid & 63;
    const int w    = tid >> 6;
    const int q    = lane >> 4, l15 = lane & 15;
    const int rt = blockIdx.x >> 5, cs = blockIdx.x & 31;
    const int rowBase = rt * 128 + w * 32;

    // --- issue DMA for jt=0 while afrag loads are in flight ---
    {
        const char* Bg = (const char*)(fbf + (cs * 256) * D_DIM);
        #pragma unroll
        for (int i = 0; i < 8; ++i) {              // 8 x 4 KB = 32 KB
            const int idx = i * 256 + tid;         // 16B chunk 0..2047
            const int col = idx >> 5;
            const int cir = idx & 31;
            __builtin_amdgcn_global_load_lds(
                (const AS1 void*)(Bg + col * 512 + ((cir ^ (col & 7)) << 4)),
                (AS3 void*)(Bs + idx * 16), 16, 0, 0);
        }
    }

    // A fragments: rows rowBase + ri*16 + l15, k = t*32 + q*8 + j
    bf16x8 afrag[8][2];
    #pragma unroll
    for (int t = 0; t < 8; ++t)
        #pragma unroll
        for (int ri = 0; ri < 2; ++ri)
            afrag[t][ri] = *(const bf16x8*)(fbf + (rowBase + ri*16 + l15) * D_DIM
                                                + t*32 + q*8);

    float rsum[2][4];
    #pragma unroll
    for (int ri = 0; ri < 2; ++ri)
        #pragma unroll
        for (int r = 0; r < 4; ++r) rsum[ri][r] = 0.f;

    for (int jt = 0; jt < 4; ++jt) {
        const int colBase = cs * 256 + jt * 64;

        __syncthreads();                           // DMA of tile jt drained

        f32x4 acc[2][4];
        #pragma unroll
        for (int ri = 0; ri < 2; ++ri)
            #pragma unroll
            for (int ci = 0; ci < 4; ++ci) acc[ri][ci] = (f32x4){0.f, 0.f, 0.f, 0.f};

        #pragma unroll
        for (int t = 0; t < 8; ++t) {
            bf16x8 bfrag[4];
            #pragma unroll
            for (int ci = 0; ci < 4; ++ci) {
                const int c   = ci * 16 + l15;     // local col 0..63
                const int cir = t * 4 + q;         // k-chunk
                bfrag[ci] = *(const bf16x8*)(Bs + c * 512 + ((cir ^ (c & 7)) << 4));
            }
            #pragma unroll
            for (int ri = 0; ri < 2; ++ri)
                #pragma unroll
                for (int ci = 0; ci < 4; ++ci)
                    acc[ri][ci] = __builtin_amdgcn_mfma_f32_16x16x32_bf16(
                        afrag[t][ri], bfrag[ci], acc[ri][ci], 0, 0, 0);
        }

        // B tile consumed; start DMA for jt+1 so it overlaps the exp epilogue
        if (jt < 3) {
            __syncthreads();                       // all waves done reading Bs
            const char* Bg = (const char*)(fbf + (colBase + 64) * D_DIM);
            #pragma unroll
            for (int i = 0; i < 8; ++i) {
                const int idx = i * 256 + tid;
                const int col = idx >> 5;
                const int cir = idx & 31;
                __builtin_amdgcn_global_load_lds(
                    (const AS1 void*)(Bg + col * 512 + ((cir ^ (col & 7)) << 4)),
                    (AS3 void*)(Bs + idx * 16), 16, 0, 0);
            }
        }

        // epilogue: e = exp2(acc*S - S); diagonal zeroed; per-row accumulate.
        // C/D layout: col=l15, row=q*4+reg. Diagonal test is per-16x16-tile
        // wave-uniform -> branch, not per-element cndmask.
        #pragma unroll
        for (int ri = 0; ri < 2; ++ri) {
            const int trow = rowBase + ri * 16;
            #pragma unroll
            for (int ci = 0; ci < 4; ++ci) {
                const int tcol = colBase + ci * 16;
                if (trow == tcol) {                // diagonal tile (rare)
                    #pragma unroll
                    for (int r = 0; r < 4; ++r) {
                        const float e = __builtin_amdgcn_exp2f(
                            __builtin_fmaf(acc[ri][ci][r], SCALE_LOG2, NEG_SCALE));
                        rsum[ri][r] += (q * 4 + r == l15) ? 0.f : e;
                    }
                } else {
                    #pragma unroll
                    for (int r = 0; r < 4; ++r)
                        rsum[ri][r] += __builtin_amdgcn_exp2f(
                            __builtin_fmaf(acc[ri][ci][r], SCALE_LOG2, NEG_SCALE));
                }
            }
        }
    }

    // reduce across the 16 lanes of each quad (cols), then atomics (4/row-grp)
    #pragma unroll
    for (int ri = 0; ri < 2; ++ri)
        #pragma unroll
        for (int r = 0; r < 4; ++r) {
            float s = rsum[ri][r];
            s += __shfl_xor(s, 1);
            s += __shfl_xor(s, 2);
            s += __shfl_xor(s, 4);
            s += __shfl_xor(s, 8);
            if (l15 == 0)
                atomicAdd(&sumexp[rowBase + ri * 16 + q * 4 + r], s);
        }
}

// ---------------- kernel 3: exact pos similarity + nll + mean --------------
__global__ __launch_bounds__(256) void k_nll(const float* __restrict__ feat,
                                             const float* __restrict__ sumexp,
                                             float* __restrict__ out) {
    __shared__ float red[4];
    const int tid = threadIdx.x, w = tid >> 6, lane = tid & 63;
    const int i  = blockIdx.x * 4 + w;
    const int pc = (i + HALF_N) & (N_ROWS - 1);
    const float4 a = ((const float4*)(feat + i  * D_DIM))[lane];
    const float4 b = ((const float4*)(feat + pc * D_DIM))[lane];
    float dab = a.x*b.x + a.y*b.y + a.z*b.z + a.w*b.w;
    float daa = a.x*a.x + a.y*a.y + a.z*a.z + a.w*a.w;
    float dbb = b.x*b.x + b.y*b.y + b.z*b.z + b.w*b.w;
    #pragma unroll
    for (int off = 32; off; off >>= 1) {
        dab += __shfl_xor(dab, off);
        daa += __shfl_xor(daa, off);
        dbb += __shfl_xor(dbb, off);
    }
    if (lane == 0) {
        const float pos = dab / (fmaxf(sqrtf(daa), EPSV) * fmaxf(sqrtf(dbb), EPSV));
        red[w] = INV_T + logf(sumexp[i]) - pos * INV_T;
    }
    __syncthreads();
    if (tid == 0)
        atomicAdd(out, (red[0] + red[1] + red[2] + red[3]) * (1.f / N_ROWS));
}

extern "C" void kernel_launch(void* const* d_in, const int* in_sizes, int n_in,
                              void* d_out, int out_size, void* d_ws, size_t ws_size,
                              hipStream_t stream) {
    const float* feat = (const float*)d_in[0];
    char* ws = (char*)d_ws;
    unsigned short* fbf = (unsigned short*)ws;                 // 4 MB bf16
    float* sumexp = (float*)(ws + 4u * 1024u * 1024u);         // 32 KB

    k_norm<<<N_ROWS / 4, 256, 0, stream>>>(feat, fbf, sumexp, (float*)d_out);
    k_sim <<<2048,       256, 0, stream>>>(fbf, sumexp);
    k_nll <<<N_ROWS / 4, 256, 0, stream>>>(feat, sumexp, (float*)d_out);
}

// Round 3
// 131.363 us; speedup vs baseline: 1.2325x; 1.2325x over previous
//
#include <hip/hip_runtime.h>
#include <hip/hip_bf16.h>
#include <math.h>

// NT-Xent loss, fused flash-style. N=8192 rows, D=256.
//   k_norm: row L2-normalize fp32 -> bf16 (ws); zero sumexp + out
//   k_sim : bf16 MFMA, exp((sim-1)/T) in-register, per-row sum atomics
//   k_nll : exact fp32 pos dot + per-row nll + mean via atomicAdd
//
// Register-budget history (the whole game so far):
//   R1: 64x64 wave tile @ (256,2): demand ~280 > 256 budget -> 183 B/lane
//       spill -> 24 MB scratch writes, 77 us.
//   R2: 32x64 tile @ (256,3): budget 512/3=168 TOTAL (unified arch+acc;
//       VGPR_Count=84 was the arch half) < ~230 demand -> 238 B/lane spill,
//       125 MB writes, 82 us.
//   R3: 32x64 tile @ (256,2): budget 256 >= ~230 demand -> no spill.
#define N_ROWS 8192
#define D_DIM  256
#define HALF_N 4096
#define INV_T      14.285714285714286f      // 1/0.07
#define SCALE_LOG2 20.609929155556620f      // log2(e)/0.07
#define NEG_SCALE  -20.609929155556620f
#define EPSV   1e-8f

typedef __attribute__((ext_vector_type(8))) short bf16x8;   // 8 bf16 = 4 VGPR
typedef __attribute__((ext_vector_type(4))) float f32x4;

#define AS1 __attribute__((address_space(1)))
#define AS3 __attribute__((address_space(3)))

__device__ inline unsigned short f2bf(float x) {
    unsigned int u = __float_as_uint(x);
    unsigned int r = (u + 0x7fffu + ((u >> 16) & 1u)) >> 16;   // RNE
    return (unsigned short)r;
}

// ---------------- kernel 1: normalize rows, emit bf16; zero accumulators ---
__global__ __launch_bounds__(256) void k_norm(const float* __restrict__ feat,
                                              unsigned short* __restrict__ fbf,
                                              float* __restrict__ sumexp,
                                              float* __restrict__ out) {
    const int tid = threadIdx.x;
    const int gid = blockIdx.x * 256 + tid;
    if (gid < N_ROWS) sumexp[gid] = 0.f;
    if (gid == 0) out[0] = 0.f;

    const int w = tid >> 6, lane = tid & 63;
    const int row = blockIdx.x * 4 + w;              // 2048 blocks * 4 rows
    const float4 v = ((const float4*)(feat + row * D_DIM))[lane];
    float ss = v.x*v.x + v.y*v.y + v.z*v.z + v.w*v.w;
    #pragma unroll
    for (int off = 32; off; off >>= 1) ss += __shfl_xor(ss, off);
    const float scale = 1.f / fmaxf(sqrtf(ss), EPSV);
    ushort4 o;
    o.x = f2bf(v.x * scale);
    o.y = f2bf(v.y * scale);
    o.z = f2bf(v.z * scale);
    o.w = f2bf(v.w * scale);
    ((ushort4*)(fbf + row * D_DIM))[lane] = o;
}

// ---------------- kernel 2: fused sim + exp + row-sum ----------------------
// grid = 2048: rt = blockIdx>>5 (64 row tiles of 128), cs = blockIdx&31
// (256-col slice). 4 waves, each owns 32 rows of the 128-row block tile.
// Per jt (4 iters): B tile 64 cols x 256 k = 32 KB LDS via global_load_lds
// w=16, XOR-16B-chunk swizzle -> conflict-free ds_read_b128 frag reads
// (SQ_LDS_BANK_CONFLICT ~0 measured). A (32 rows x 256 k) in regs: 64 VGPR.
// DMA for tile jt+1 issued before the exp epilogue of tile jt (overlap).
__global__ __launch_bounds__(256, 2) void k_sim(const unsigned short* __restrict__ fbf,
                                                float* __restrict__ sumexp) {
    __shared__ __align__(16) char Bs[32768];
    const int tid  = threadIdx.x;
    const int lane = tid & 63;
    const int w    = tid >> 6;
    const int q    = lane >> 4, l15 = lane & 15;
    const int rt = blockIdx.x >> 5, cs = blockIdx.x & 31;
    const int rowBase = rt * 128 + w * 32;

    // --- issue DMA for jt=0 while afrag loads are in flight ---
    {
        const char* Bg = (const char*)(fbf + (cs * 256) * D_DIM);
        #pragma unroll
        for (int i = 0; i < 8; ++i) {              // 8 x 4 KB = 32 KB
            const int idx = i * 256 + tid;         // 16B chunk 0..2047
            const int col = idx >> 5;
            const int cir = idx & 31;
            __builtin_amdgcn_global_load_lds(
                (const AS1 void*)(Bg + col * 512 + ((cir ^ (col & 7)) << 4)),
                (AS3 void*)(Bs + idx * 16), 16, 0, 0);
        }
    }

    // A fragments: rows rowBase + ri*16 + l15, k = t*32 + q*8 + j
    bf16x8 afrag[8][2];
    #pragma unroll
    for (int t = 0; t < 8; ++t)
        #pragma unroll
        for (int ri = 0; ri < 2; ++ri)
            afrag[t][ri] = *(const bf16x8*)(fbf + (rowBase + ri*16 + l15) * D_DIM
                                                + t*32 + q*8);

    float rsum[2][4];
    #pragma unroll
    for (int ri = 0; ri < 2; ++ri)
        #pragma unroll
        for (int r = 0; r < 4; ++r) rsum[ri][r] = 0.f;

    #pragma unroll 1                               // keep DMA live ranges tight
    for (int jt = 0; jt < 4; ++jt) {
        const int colBase = cs * 256 + jt * 64;

        __syncthreads();                           // DMA of tile jt drained

        f32x4 acc[2][4];
        #pragma unroll
        for (int ri = 0; ri < 2; ++ri)
            #pragma unroll
            for (int ci = 0; ci < 4; ++ci) acc[ri][ci] = (f32x4){0.f, 0.f, 0.f, 0.f};

        #pragma unroll
        for (int t = 0; t < 8; ++t) {
            bf16x8 bfrag[4];
            #pragma unroll
            for (int ci = 0; ci < 4; ++ci) {
                const int c   = ci * 16 + l15;     // local col 0..63
                const int cir = t * 4 + q;         // k-chunk
                bfrag[ci] = *(const bf16x8*)(Bs + c * 512 + ((cir ^ (c & 7)) << 4));
            }
            #pragma unroll
            for (int ri = 0; ri < 2; ++ri)
                #pragma unroll
                for (int ci = 0; ci < 4; ++ci)
                    acc[ri][ci] = __builtin_amdgcn_mfma_f32_16x16x32_bf16(
                        afrag[t][ri], bfrag[ci], acc[ri][ci], 0, 0, 0);
        }

        // B tile consumed; start DMA for jt+1 so it overlaps the exp epilogue
        if (jt < 3) {
            __syncthreads();                       // all waves done reading Bs
            const char* Bg = (const char*)(fbf + (colBase + 64) * D_DIM);
            #pragma unroll
            for (int i = 0; i < 8; ++i) {
                const int idx = i * 256 + tid;
                const int col = idx >> 5;
                const int cir = idx & 31;
                __builtin_amdgcn_global_load_lds(
                    (const AS1 void*)(Bg + col * 512 + ((cir ^ (col & 7)) << 4)),
                    (AS3 void*)(Bs + idx * 16), 16, 0, 0);
            }
        }

        // epilogue: e = exp2(acc*S - S); diagonal zeroed; per-row accumulate.
        // C/D layout: col=l15, row=q*4+reg. Diagonal test is per-16x16-tile
        // wave-uniform -> branch, not per-element cndmask.
        #pragma unroll
        for (int ri = 0; ri < 2; ++ri) {
            const int trow = rowBase + ri * 16;
            #pragma unroll
            for (int ci = 0; ci < 4; ++ci) {
                const int tcol = colBase + ci * 16;
                if (trow == tcol) {                // diagonal tile (rare)
                    #pragma unroll
                    for (int r = 0; r < 4; ++r) {
                        const float e = __builtin_amdgcn_exp2f(
                            __builtin_fmaf(acc[ri][ci][r], SCALE_LOG2, NEG_SCALE));
                        rsum[ri][r] += (q * 4 + r == l15) ? 0.f : e;
                    }
                } else {
                    #pragma unroll
                    for (int r = 0; r < 4; ++r)
                        rsum[ri][r] += __builtin_amdgcn_exp2f(
                            __builtin_fmaf(acc[ri][ci][r], SCALE_LOG2, NEG_SCALE));
                }
            }
        }
    }

    // reduce across the 16 lanes of each quad (cols), then atomics (4/row-grp)
    #pragma unroll
    for (int ri = 0; ri < 2; ++ri)
        #pragma unroll
        for (int r = 0; r < 4; ++r) {
            float s = rsum[ri][r];
            s += __shfl_xor(s, 1);
            s += __shfl_xor(s, 2);
            s += __shfl_xor(s, 4);
            s += __shfl_xor(s, 8);
            if (l15 == 0)
                atomicAdd(&sumexp[rowBase + ri * 16 + q * 4 + r], s);
        }
}

// ---------------- kernel 3: exact pos similarity + nll + mean --------------
__global__ __launch_bounds__(256) void k_nll(const float* __restrict__ feat,
                                             const float* __restrict__ sumexp,
                                             float* __restrict__ out) {
    __shared__ float red[4];
    const int tid = threadIdx.x, w = tid >> 6, lane = tid & 63;
    const int i  = blockIdx.x * 4 + w;
    const int pc = (i + HALF_N) & (N_ROWS - 1);
    const float4 a = ((const float4*)(feat + i  * D_DIM))[lane];
    const float4 b = ((const float4*)(feat + pc * D_DIM))[lane];
    float dab = a.x*b.x + a.y*b.y + a.z*b.z + a.w*b.w;
    float daa = a.x*a.x + a.y*a.y + a.z*a.z + a.w*a.w;
    float dbb = b.x*b.x + b.y*b.y + b.z*b.z + b.w*b.w;
    #pragma unroll
    for (int off = 32; off; off >>= 1) {
        dab += __shfl_xor(dab, off);
        daa += __shfl_xor(daa, off);
        dbb += __shfl_xor(dbb, off);
    }
    if (lane == 0) {
        const float pos = dab / (fmaxf(sqrtf(daa), EPSV) * fmaxf(sqrtf(dbb), EPSV));
        red[w] = INV_T + logf(sumexp[i]) - pos * INV_T;
    }
    __syncthreads();
    if (tid == 0)
        atomicAdd(out, (red[0] + red[1] + red[2] + red[3]) * (1.f / N_ROWS));
}

extern "C" void kernel_launch(void* const* d_in, const int* in_sizes, int n_in,
                              void* d_out, int out_size, void* d_ws, size_t ws_size,
                              hipStream_t stream) {
    const float* feat = (const float*)d_in[0];
    char* ws = (char*)d_ws;
    unsigned short* fbf = (unsigned short*)ws;                 // 4 MB bf16
    float* sumexp = (float*)(ws + 4u * 1024u * 1024u);         // 32 KB

    k_norm<<<N_ROWS / 4, 256, 0, stream>>>(feat, fbf, sumexp, (float*)d_out);
    k_sim <<<2048,       256, 0, stream>>>(fbf, sumexp);
    k_nll <<<N_ROWS / 4, 256, 0, stream>>>(feat, sumexp, (float*)d_out);
}